// Round 8
// baseline (404.845 us; speedup 1.0000x reference)
//
#include <hip/hip_runtime.h>
#include <hip/hip_bf16.h>
#include <math.h>

// NeRF coarse renderer, fused MFMA implementation, fp16 trunk + fp32 exact
// last-sample density side-channel.
// WHY: INF_DELTA=1e10 makes alpha_63 = 1-exp(-relu(density_63)*1e10) a step
// function of sign(density_63). Any finite trunk noise flips rays whose true
// density_63 ~ 0, giving ~0.37 absmax regardless of dtype (measured: bf16
// 0.383, fp16 0.367 bit-identical across two structures). Samples 0..62 are
// smooth -> fp16 trunk fine. So: fp16 MFMA trunk for all 64 samples + a
// 256-thread fp32 VALU MLP recomputing ONLY sample 63's density exactly.
// Block = 1 ray = 64 rows; 512 threads = 2 row-groups x 4 col-groups; RT=2.
// LDS ~40.3 KB -> 4 blocks/CU.

typedef unsigned short u16;
typedef unsigned int   u32;
typedef _Float16 f16;
typedef _Float16 f16x8 __attribute__((ext_vector_type(8)));
typedef float    f32x4 __attribute__((ext_vector_type(4)));

#define ACT_STRIDE 296   // f16 elems; 592B rows; 16B-aligned b128 accesses
#define NROW 64

// Repacked fp16 weights (MFMA A-operand fragments):
// W1(16384) W2(65536) W3(65536) Wfeat(65536) Wdir(36864)
__device__ __align__(16) f16 g_w[249856];

constexpr int OFF_W1 = 0;
constexpr int OFF_W2 = 16384;
constexpr int OFF_W3 = 81920;
constexpr int OFF_WF = 147456;
constexpr int OFF_WD = 212992;

static __device__ __forceinline__ float wash(float x) { // NaN -> 0
  return (x == x) ? x : 0.0f;
}

struct alignas(8) F16x4 { f16 x, y, z, w; };

// ---------------------------------------------------------------------------
// Weight repack (f32 -> f16) into A-operand fragments of
// mfma_f32_16x16x32_f16 (A := W^T tile): element pos = lane*8 + j of
// fragment (t,s) holds W[s*32 + (lane>>4)*8 + j][t*16 + (lane&15)]
// (zero-padded for k >= K; W1: 63->64, Wdir: 283->288).
// ---------------------------------------------------------------------------
__global__ void repack_kernel(const float* __restrict__ w1, const float* __restrict__ w2,
                              const float* __restrict__ w3, const float* __restrict__ wf,
                              const float* __restrict__ wd) {
  int e = blockIdx.x * 256 + threadIdx.x;
  const float* src; int K, N, ks, base;
  if (e < 81920)       { if (e < 16384) { src = w1; K = 63;  N = 256; ks = 2; base = OFF_W1; }
                         else           { src = w2; K = 256; N = 256; ks = 8; base = OFF_W2; } }
  else if (e < 147456) { src = w3; K = 256; N = 256; ks = 8; base = OFF_W3; }
  else if (e < 212992) { src = wf; K = 256; N = 256; ks = 8; base = OFF_WF; }
  else                 { src = wd; K = 283; N = 128; ks = 9; base = OFF_WD; }
  int le   = e - base;
  int f    = le >> 9, pos = le & 511;
  int lane = pos >> 3, j = pos & 7;
  int t    = f / ks,  s = f - t * ks;
  int k    = s * 32 + ((lane >> 4) << 3) + j;
  int n    = (t << 4) + (lane & 15);
  g_w[e] = (k < K) ? (f16)src[k * N + n] : (f16)0.0f;
}

// ---------------------------------------------------------------------------
// One dense fp16 layer on the shared activation buffer, in place.
// 8 waves = 2 row-groups (rg) x 4 col-groups (cg); wave computes RT row-tiles
// x NT col-tiles. fp32 accumulate; k-loop reads, sync, writeback, sync.
// ---------------------------------------------------------------------------
template<int KS, int NT, int RT, bool RELU>
static __device__ __forceinline__ void mlp_layer(f16* act,
                                                 const f16* __restrict__ w_,
                                                 const float* __restrict__ bias,
                                                 int rg, int cg, int lane) {
  f32x4 acc[RT][NT];
#pragma unroll
  for (int rt = 0; rt < RT; ++rt)
#pragma unroll
    for (int nt = 0; nt < NT; ++nt) {
      f32x4 z = {0.0f, 0.0f, 0.0f, 0.0f};
      acc[rt][nt] = z;
    }
  const int l15 = lane & 15, q = lane >> 4;
#pragma unroll
  for (int s = 0; s < KS; ++s) {
    f16x8 af[RT];
#pragma unroll
    for (int rt = 0; rt < RT; ++rt) {
      const int row = (rg * RT + rt) * 16 + l15;
      af[rt] = *reinterpret_cast<const f16x8*>(&act[row * ACT_STRIDE + s * 32 + q * 8]);
    }
    f16x8 wf[NT];
#pragma unroll
    for (int nt = 0; nt < NT; ++nt) {
      const int t = cg * NT + nt;
      wf[nt] = *reinterpret_cast<const f16x8*>(&w_[(t * KS + s) * 512 + lane * 8]);
    }
#pragma unroll
    for (int rt = 0; rt < RT; ++rt)
#pragma unroll
      for (int nt = 0; nt < NT; ++nt)
        acc[rt][nt] = __builtin_amdgcn_mfma_f32_16x16x32_f16(
            wf[nt], af[rt], acc[rt][nt], 0, 0, 0);
  }
  __syncthreads();   // all reads of act complete before overwrite
#pragma unroll
  for (int nt = 0; nt < NT; ++nt) {
    const int nb = (cg * NT + nt) * 16 + q * 4;
    const float b0 = bias[nb + 0], b1 = bias[nb + 1];
    const float b2 = bias[nb + 2], b3 = bias[nb + 3];
#pragma unroll
    for (int rt = 0; rt < RT; ++rt) {
      const int row = (rg * RT + rt) * 16 + l15;
      float v0 = acc[rt][nt][0] + b0;
      float v1 = acc[rt][nt][1] + b1;
      float v2 = acc[rt][nt][2] + b2;
      float v3 = acc[rt][nt][3] + b3;
      if (RELU) {
        v0 = fmaxf(v0, 0.0f); v1 = fmaxf(v1, 0.0f);
        v2 = fmaxf(v2, 0.0f); v3 = fmaxf(v3, 0.0f);
      }
      F16x4 o; o.x = (f16)v0; o.y = (f16)v1; o.z = (f16)v2; o.w = (f16)v3;
      *reinterpret_cast<F16x4*>(&act[row * ACT_STRIDE + nb]) = o;
    }
  }
  __syncthreads();
}

// ---------------------------------------------------------------------------
// Main fused kernel. Block b = ray b; row = sample index (0..63); 512 threads.
// ---------------------------------------------------------------------------
__global__ __launch_bounds__(512, 4)
void nerf_kernel(const float* __restrict__ xyz, const float* __restrict__ vdirs,
                 const float* __restrict__ w1f, const float* __restrict__ b1,
                 const float* __restrict__ w2f, const float* __restrict__ b2,
                 const float* __restrict__ w3f, const float* __restrict__ b3,
                 const float* __restrict__ wsig, const float* __restrict__ bsig,
                 const float* __restrict__ bfeat, const float* __restrict__ bdir,
                 const float* __restrict__ wrgb, const float* __restrict__ brgb,
                 float* __restrict__ out) {
  __shared__ f16  s_act[NROW * ACT_STRIDE];   // 37888 B
  __shared__ float s_geo[6];                  // xyz[3], normalized vd[3]
  __shared__ float s_de[32];                  // dir posenc (27) + zero pad
  __shared__ float s_pe[64];                  // fp32 posenc of sample 63
  __shared__ float s_h0[256], s_h1[256];      // fp32 side-channel ping-pong
  __shared__ float s_sig;                     // exact density of sample 63

  const int tid  = threadIdx.x;
  const int wave = tid >> 6;
  const int lane = tid & 63;
  const int rg   = wave >> 2;                 // row-group 0..1
  const int cg   = wave & 3;                  // col-group 0..3

  // --- Phase A1: ray geometry (1 thread) ---
  if (tid == 0) {
    int rgI = blockIdx.x;
    float vx = vdirs[rgI * 3 + 0];
    float vy = vdirs[rgI * 3 + 1];
    float vz = vdirs[rgI * 3 + 2];
    float inv = 1.0f / sqrtf(vx * vx + vy * vy + vz * vz + 1e-20f);
    s_geo[0] = xyz[rgI * 3 + 0];
    s_geo[1] = xyz[rgI * 3 + 1];
    s_geo[2] = xyz[rgI * 3 + 2];
    s_geo[3] = vx * inv;
    s_geo[4] = vy * inv;
    s_geo[5] = vz * inv;
  }
  __syncthreads();

  // --- Phase A2: direction posenc (32 threads), 27 feats + zero pad ---
  if (tid < 32) {
    float val = 0.0f;
    if (tid < 3) val = s_geo[3 + tid];
    else if (tid < 27) {
      int fi = tid - 3, l = fi / 6, m = fi % 6;
      int ii = (m < 3) ? m : m - 3;
      float ang = s_geo[3 + ii] * (float)(1 << l);
      val = (m < 3) ? sinf(ang) : cosf(ang);
    }
    s_de[tid] = val;
  }

  // --- Phase A3: fp32 posenc of sample 63 (ts = FAR = 6.0 exactly) ---
  if (tid >= 64 && tid < 128) {
    int f = tid - 64;
    float p[3];
    p[0] = s_geo[0] + 6.0f * s_geo[3];
    p[1] = s_geo[1] + 6.0f * s_geo[4];
    p[2] = s_geo[2] + 6.0f * s_geo[5];
    float val = 0.0f;
    if (f < 3) val = p[f];
    else if (f < 63) {
      int fi = f - 3, l = fi / 6, m = fi % 6;
      int ii = (m < 3) ? m : m - 3;
      float ang = p[ii] * (float)(1 << l);
      val = (m < 3) ? sinf(ang) : cosf(ang);
    }
    s_pe[f] = val;
  }

  // --- Phase B: sample points + posenc(L=10) -> cols 0..63 (63 zero) ---
  {
    int row = tid >> 3, c8 = tid & 7;
    float t  = (float)row * (1.0f / 63.0f);
    float ts = 2.0f * (1.0f - t) + 6.0f * t;
    float p[3];
    p[0] = s_geo[0] + ts * s_geo[3];
    p[1] = s_geo[1] + ts * s_geo[4];
    p[2] = s_geo[2] + ts * s_geo[5];
#pragma unroll
    for (int j = 0; j < 8; ++j) {
      int f = c8 * 8 + j;
      float val;
      if (f < 3) val = p[f];
      else if (f == 63) val = 0.0f;
      else {
        int fi = f - 3, l = fi / 6, m = fi % 6;
        int ii = (m < 3) ? m : m - 3;
        float ang = p[ii] * (float)(1 << l);
        val = (m < 3) ? sinf(ang) : cosf(ang);
      }
      s_act[row * ACT_STRIDE + f] = (f16)val;
    }
  }
  __syncthreads();

  // --- fp32 side-channel: exact density for sample 63 (step-function fix).
  //     Coalesced column reads: W[k*256+t] consecutive in t for fixed k. ---
  if (tid < 256) {
    float a = b1[tid];
    for (int k = 0; k < 63; ++k) a = fmaf(w1f[k * 256 + tid], s_pe[k], a);
    s_h0[tid] = fmaxf(a, 0.0f);
  }
  __syncthreads();
  if (tid < 256) {
    float a = b2[tid];
#pragma unroll 4
    for (int k = 0; k < 256; ++k) a = fmaf(w2f[k * 256 + tid], s_h0[k], a);
    s_h1[tid] = fmaxf(a, 0.0f);
  }
  __syncthreads();
  if (tid < 256) {
    float a = b3[tid];
#pragma unroll 4
    for (int k = 0; k < 256; ++k) a = fmaf(w3f[k * 256 + tid], s_h1[k], a);
    s_h0[tid] = fmaxf(a, 0.0f);
  }
  __syncthreads();
  if (tid < 64) {
    float a = s_h0[tid * 4 + 0] * wsig[tid * 4 + 0]
            + s_h0[tid * 4 + 1] * wsig[tid * 4 + 1]
            + s_h0[tid * 4 + 2] * wsig[tid * 4 + 2]
            + s_h0[tid * 4 + 3] * wsig[tid * 4 + 3];
#pragma unroll
    for (int o = 32; o > 0; o >>= 1) a += __shfl_xor(a, o, 64);
    if (tid == 0) s_sig = wash(a + bsig[0]);
  }
  // visibility: trunk layers below contain multiple __syncthreads before use

  // --- MLP trunk (fp16 MFMA) ---
  mlp_layer<2, 4, 2, true>(s_act, g_w + OFF_W1, b1, rg, cg, lane);   // 63(+1)->256
  mlp_layer<8, 4, 2, true>(s_act, g_w + OFF_W2, b2, rg, cg, lane);   // 256->256
  mlp_layer<8, 4, 2, true>(s_act, g_w + OFF_W3, b3, rg, cg, lane);   // 256->256

  // --- sigma head (fp32 weights): reads h3 before feat layer's writeback ---
  float my_den = 0.0f;
  if (tid < 64) {
    float a = 0.0f;
    const float4* wp = reinterpret_cast<const float4*>(wsig);
#pragma unroll 8
    for (int k4 = 0; k4 < 64; ++k4) {
      F16x4 h = *reinterpret_cast<const F16x4*>(&s_act[tid * ACT_STRIDE + k4 * 4]);
      float4 w = wp[k4];
      a += (float)h.x * w.x + (float)h.y * w.y + (float)h.z * w.z + (float)h.w * w.w;
    }
    my_den = wash(a + bsig[0]);
  }
  // ordering safe: feat layer's internal __syncthreads precedes its writes

  mlp_layer<8, 4, 2, false>(s_act, g_w + OFF_WF, bfeat, rg, cg, lane); // feat

  // --- append direction encoding: cols 256..287 (283..287 zero via pad) ---
  {
    int row = tid >> 3, i0 = (tid & 7) * 4;
#pragma unroll
    for (int j = 0; j < 4; ++j)
      s_act[row * ACT_STRIDE + 256 + i0 + j] = (f16)s_de[i0 + j];
  }
  __syncthreads();

  mlp_layer<9, 2, 2, true>(s_act, g_w + OFF_WD, bdir, rg, cg, lane);  // 283(+5)->128

  // --- rgb head (fp32 weights) ---
  float r0 = 0.0f, r1 = 0.0f, r2 = 0.0f;
  if (tid < 64) {
    float a0 = brgb[0], a1 = brgb[1], a2 = brgb[2];
#pragma unroll 8
    for (int k = 0; k < 128; ++k) {
      float hv = (float)s_act[tid * ACT_STRIDE + k];
      a0 += hv * wrgb[k * 3 + 0];
      a1 += hv * wrgb[k * 3 + 1];
      a2 += hv * wrgb[k * 3 + 2];
    }
    a0 = wash(a0); a1 = wash(a1); a2 = wash(a2);
    r0 = 1.0f / (1.0f + expf(-a0));
    r1 = 1.0f / (1.0f + expf(-a1));
    r2 = 1.0f / (1.0f + expf(-a2));
  }

  // --- Phase D: volume render (wave 0; lane = sample) ---
  if (wave == 0) {
    int rgI = blockIdx.x;
    float t  = (float)lane * (1.0f / 63.0f);
    float ts = 2.0f * (1.0f - t) + 6.0f * t;
    float delta;
    if (lane < 63) {
      float t2 = (float)(lane + 1) * (1.0f / 63.0f);
      delta = (2.0f * (1.0f - t2) + 6.0f * t2) - ts;
    } else delta = 1e10f;
    float den = (lane == 63) ? s_sig : my_den;   // exact fp32 for sample 63
    float sig = fmaxf(den, 0.0f);
    float sd  = fminf(sig * delta, 60.0f);   // exp(-60)~1e-26: same semantics
    // exclusive prefix sum of sd across the 64-lane wave
    float incl = sd;
#pragma unroll
    for (int o = 1; o < 64; o <<= 1) {
      float v = __shfl_up(incl, o, 64);
      if (lane >= o) incl += v;
    }
    float excl  = fminf(fmaxf(incl - sd, 0.0f), 60.0f);
    float T     = expf(-excl);
    float alpha = 1.0f - expf(-sd);
    float w     = T * alpha;
    float sw = w, swr = w * r0, swg = w * r1, swb = w * r2, swd = w * ts;
#pragma unroll
    for (int o = 32; o > 0; o >>= 1) {
      sw  += __shfl_xor(sw,  o, 64);
      swr += __shfl_xor(swr, o, 64);
      swg += __shfl_xor(swg, o, 64);
      swb += __shfl_xor(swb, o, 64);
      swd += __shfl_xor(swd, o, 64);
    }
    if (lane == 0) {
      float bg = 1.0f - sw;               // white background
      out[rgI * 3 + 0]  = swr + bg;
      out[rgI * 3 + 1]  = swg + bg;
      out[rgI * 3 + 2]  = swb + bg;
      out[12288 + rgI]  = swd;            // depth_map
      out[16384 + rgI]  = sw;             // alpha_map
    }
  }
}

extern "C" void kernel_launch(void* const* d_in, const int* in_sizes, int n_in,
                              void* d_out, int out_size, void* d_ws, size_t ws_size,
                              hipStream_t stream) {
  const float* xyz   = (const float*)d_in[0];
  const float* vdirs = (const float*)d_in[1];
  const float* W1    = (const float*)d_in[2];
  const float* b1    = (const float*)d_in[3];
  const float* W2    = (const float*)d_in[4];
  const float* b2    = (const float*)d_in[5];
  const float* W3    = (const float*)d_in[6];
  const float* b3    = (const float*)d_in[7];
  const float* Wsig  = (const float*)d_in[8];
  const float* bsig  = (const float*)d_in[9];
  const float* Wfeat = (const float*)d_in[10];
  const float* bfeat = (const float*)d_in[11];
  const float* Wdir  = (const float*)d_in[12];
  const float* bdir  = (const float*)d_in[13];
  const float* Wrgb  = (const float*)d_in[14];
  const float* brgb  = (const float*)d_in[15];
  float* out = (float*)d_out;

  repack_kernel<<<dim3(976), dim3(256), 0, stream>>>(W1, W2, W3, Wfeat, Wdir);
  nerf_kernel<<<dim3(4096), dim3(512), 0, stream>>>(
      xyz, vdirs, W1, b1, W2, b2, W3, b3, Wsig, bsig, bfeat, bdir, Wrgb, brgb, out);
}